// Round 1
// baseline (109.696 us; speedup 1.0000x reference)
//
#include <hip/hip_runtime.h>
#include <hip/hip_bf16.h>

// ColumnConsistencyLoss: B=16, T=8192, C=128.
// out = mean over columns c with n_c>1 of (q_c - t_c/n_c)/(n_c*C)
//   n_c = # valid rows with seg=c ; q_c = sum z2/z^2 over those rows
//   s[c][j] = sum p_j over those rows ; t_c = sum_j s[c][j]^2
//
// Round-9: two dispatches. fused_kernel unchanged from round-8 (phase-1
// softmax is HBM-bound at the 64 MB logits floor; grid=256 = 1 block/CU so
// the slab-store tail cannot overlap — verified round-8 analysis). New:
//  - final_k folded into k3 via last-block-done atomics (acc zeroed by
//    fused_kernel block 0; kernel-boundary ordering guarantees visibility).
//  - k3 slab reduction vectorized to float4 (was 32 scalar dword loads per
//    thread), single __syncthreads stage, n/q reduced concurrently by
//    waves 1-2.
// ~85-90 us of dur_us is harness ws-poison (268 MB fill @ 6.5 TB/s) +
// d_in restore — not addressable from kernel code.

#define NROWS 131072
#define CC    128
#define NB    256
#define RPB   512   // rows per block

typedef float f32x16 __attribute__((ext_vector_type(16)));
typedef short bf16x8 __attribute__((ext_vector_type(8)));

union U4V { uint4 u; bf16x8 v; };
union H2U { __hip_bfloat162 h; unsigned int u; };

// ---------------- Fused: softmax -> LDS P -> one-hot MFMA -> partial slab ---
// 256 blocks x 1024 thr (16 waves).
// Phase 1 (all 16 waves): wave handles 32 rows = ksteps 2w,2w+1.
//   lane = 32q + j5 ; rows rb..rb+7 in half q; P packed to LDS in MFMA
//   B-fragment order (hardware-verified round 7: absmax 0.0).
// Phase 2 (waves 0-3): wave = m-tile (32 c's), 32 ksteps, 4 n-tiles,
//   b-frags via ds_read_b128 from the LDS staged P.
__global__ __launch_bounds__(1024) void fused_kernel(
    const float* __restrict__ logits, const int* __restrict__ seg,
    const int* __restrict__ mask, float* __restrict__ slab_s,
    float* __restrict__ slab_n, float* __restrict__ slab_q,
    float* __restrict__ acc) {
  __shared__ ushort Plds[RPB * CC];        // 128 KiB
  __shared__ int sm[RPB];                  // 2 KiB: seg | mask<<16
  __shared__ unsigned int sg4[128];        // 512 B: packed seg-bytes (255=inv)
  __shared__ float n_lds[CC], q_lds[CC];   // 1 KiB
  const int t = threadIdx.x, b = blockIdx.x;
  if (b == 0 && t < 4) ((unsigned int*)acc)[t] = 0u;  // zero (total,count,done)
  if (t < CC) { n_lds[t] = 0.f; q_lds[t] = 0.f; }
  if (t < RPB) {
    const int r = b * RPB + t;
    sm[t] = seg[r] | (mask[r] << 16);
  }
  __syncthreads();
  if (t < 128) {
    unsigned int w = 0;
#pragma unroll
    for (int k = 0; k < 4; ++k) {
      const int smv = sm[t * 4 + k];
      const unsigned int sv = (smv >> 16) ? (unsigned int)(smv & 0xFFFF) : 255u;
      w |= sv << (8 * k);
    }
    sg4[t] = w;
  }

  const int wave = t >> 6, lane = t & 63;
  const int q = lane >> 5, j5 = lane & 31;
#pragma unroll
  for (int g = 0; g < 2; ++g) {
    const int ts = 2 * wave + g;           // kstep in [0,32)
    const int rb = ts * 16 + q * 8;        // local row base (+i)
    float x[8][4];
#pragma unroll
    for (int i = 0; i < 8; ++i) {
      const float* rp = logits + (size_t)(b * RPB + rb + i) * CC + j5;
#pragma unroll
      for (int nt = 0; nt < 4; ++nt) x[i][nt] = rp[nt * 32];
    }
    float inv[8], qr[8];
#pragma unroll
    for (int i = 0; i < 8; ++i) {
      float z = 0.f, z2 = 0.f;
#pragma unroll
      for (int nt = 0; nt < 4; ++nt) {
        const float e = __expf(x[i][nt]);
        x[i][nt] = e; z += e; z2 += e * e;
      }
#pragma unroll
      for (int off = 1; off < 32; off <<= 1) {  // 32-lane halves hold rows
        z  += __shfl_xor(z, off, 64);
        z2 += __shfl_xor(z2, off, 64);
      }
      inv[i] = 1.0f / z;
      qr[i] = z2 * inv[i] * inv[i];
    }
#pragma unroll
    for (int nt = 0; nt < 4; ++nt) {
      unsigned int d[4];
#pragma unroll
      for (int k = 0; k < 4; ++k) {
        H2U h;
        h.h = __float22bfloat162_rn(make_float2(
            x[2 * k][nt] * inv[2 * k], x[2 * k + 1][nt] * inv[2 * k + 1]));
        d[k] = h.u;
      }
      *(uint4*)(Plds + ((size_t)(ts * 4 + nt) * 64 + lane) * 8) =
          make_uint4(d[0], d[1], d[2], d[3]);
    }
    if (j5 == 0) {
#pragma unroll
      for (int i = 0; i < 8; ++i) {
        const int smv = sm[rb + i];
        if (smv >> 16) {
          atomicAdd(&n_lds[smv & 0xFFFF], 1.0f);
          atomicAdd(&q_lds[smv & 0xFFFF], qr[i]);
        }
      }
    }
  }
  __syncthreads();

  // n/q slab write by waves 4-7 (GEMM waves start immediately).
  if (t >= 256 && t < 384) slab_n[(t - 256) * NB + b] = n_lds[t - 256];
  else if (t >= 384 && t < 512) slab_q[(t - 384) * NB + b] = q_lds[t - 384];

  if (wave < 4) {
    const int mm = wave * 32 + (lane & 31);
    f32x16 acc0 = {}, acc1 = {}, acc2 = {}, acc3 = {};
    const ushort* pl = Plds + (size_t)lane * 8;
    for (int ks = 0; ks < 32; ++ks) {
      const unsigned int w0 = sg4[ks * 4 + q * 2];
      const unsigned int w1 = sg4[ks * 4 + q * 2 + 1];
      U4V a;
      {
        const unsigned int s0 = w0 & 255u, s1 = (w0 >> 8) & 255u;
        const unsigned int s2 = (w0 >> 16) & 255u, s3 = w0 >> 24;
        const unsigned int s4 = w1 & 255u, s5 = (w1 >> 8) & 255u;
        const unsigned int s6 = (w1 >> 16) & 255u, s7 = w1 >> 24;
        const unsigned int um = (unsigned int)mm;
        a.u = make_uint4(
            (s0 == um ? 0x3F80u : 0u) | (s1 == um ? 0x3F800000u : 0u),
            (s2 == um ? 0x3F80u : 0u) | (s3 == um ? 0x3F800000u : 0u),
            (s4 == um ? 0x3F80u : 0u) | (s5 == um ? 0x3F800000u : 0u),
            (s6 == um ? 0x3F80u : 0u) | (s7 == um ? 0x3F800000u : 0u));
      }
      U4V b0, b1, b2, b3;
      b0.u = *(const uint4*)(pl + (size_t)(ks * 4 + 0) * 512);
      b1.u = *(const uint4*)(pl + (size_t)(ks * 4 + 1) * 512);
      b2.u = *(const uint4*)(pl + (size_t)(ks * 4 + 2) * 512);
      b3.u = *(const uint4*)(pl + (size_t)(ks * 4 + 3) * 512);
      acc0 = __builtin_amdgcn_mfma_f32_32x32x16_bf16(a.v, b0.v, acc0, 0, 0, 0);
      acc1 = __builtin_amdgcn_mfma_f32_32x32x16_bf16(a.v, b1.v, acc1, 0, 0, 0);
      acc2 = __builtin_amdgcn_mfma_f32_32x32x16_bf16(a.v, b2.v, acc2, 0, 0, 0);
      acc3 = __builtin_amdgcn_mfma_f32_32x32x16_bf16(a.v, b3.v, acc3, 0, 0, 0);
    }
    // C/D layout (verified m74/m101 + round-7 absmax 0.0):
    // col = lane&31, row = (reg&3) + 8*(reg>>2) + 4*(lane>>5)
    float* outp = slab_s + (size_t)b * (CC * CC);
    const int jcol = lane & 31;
    const int rbase = (lane >> 5) * 4;
#pragma unroll
    for (int reg = 0; reg < 16; ++reg) {
      const int c = wave * 32 + (reg & 3) + 8 * (reg >> 2) + rbase;
      outp[c * CC + 0 * 32 + jcol] = acc0[reg];
      outp[c * CC + 1 * 32 + jcol] = acc1[reg];
      outp[c * CC + 2 * 32 + jcol] = acc2[reg];
      outp[c * CC + 3 * 32 + jcol] = acc3[reg];
    }
  }
}

// ---------------- K3: reduce partials -> colvar -> atomic-merge -> out ------
// 128 blocks (one per column c) x 1024 thr (16 waves).
// Stage A (all waves): float4 slab_s reduction. thread (g0 = t>>5, v = t&31)
// sums slabs {g0 + 32i} for float4 column-quad v -> LDS part[g0][v];
// wave 0 then folds the 32 g-groups and squares.
// Stage B (waves 1,2, concurrent): n/q slab rows.
// Epilogue: per-block (cv, flag) atomicAdd into acc; last block writes out.
__global__ __launch_bounds__(1024) void k3_colvar(
    const float* __restrict__ slab_s, const float* __restrict__ slab_n,
    const float* __restrict__ slab_q, float* __restrict__ acc,
    float* __restrict__ out) {
  const int c = blockIdx.x, t = threadIdx.x;
  const int v = t & 31, g0 = t >> 5;
  __shared__ float4 part[32][32];          // 16 KiB
  {
    const float4* base = (const float4*)slab_s +
                         (size_t)g0 * (CC * CC / 4) + c * (CC / 4) + v;
    float4 a = make_float4(0.f, 0.f, 0.f, 0.f);
#pragma unroll
    for (int i = 0; i < 8; ++i) {
      const float4 x = base[(size_t)(32 * i) * (CC * CC / 4)];
      a.x += x.x; a.y += x.y; a.z += x.z; a.w += x.w;
    }
    part[g0][v] = a;
  }
  float np = 0.f, qp = 0.f;
  if (t >= 64 && t < 128) {                // wave 1: n row (256 floats)
    const int k = t - 64;
#pragma unroll
    for (int i = 0; i < 4; ++i) np += slab_n[c * NB + k + 64 * i];
  } else if (t >= 128 && t < 192) {        // wave 2: q row
    const int k = t - 128;
#pragma unroll
    for (int i = 0; i < 4; ++i) qp += slab_q[c * NB + k + 64 * i];
  }
  __syncthreads();
  float tp = 0.f;
  if (t < 32) {                            // wave 0: fold 32 g-groups, square
    float4 s = make_float4(0.f, 0.f, 0.f, 0.f);
#pragma unroll
    for (int g = 0; g < 32; ++g) {
      const float4 x = part[g][v];
      s.x += x.x; s.y += x.y; s.z += x.z; s.w += x.w;
    }
    tp = s.x * s.x + s.y * s.y + s.z * s.z + s.w * s.w;
  }
#pragma unroll
  for (int off = 1; off < 64; off <<= 1) { // wave0: tp; wave1: np; wave2: qp
    tp += __shfl_xor(tp, off, 64);
    np += __shfl_xor(np, off, 64);
    qp += __shfl_xor(qp, off, 64);
  }
  __shared__ float fin[3];
  if (t == 0) fin[0] = tp;
  else if (t == 64) fin[1] = np;
  else if (t == 128) fin[2] = qp;
  __syncthreads();
  if (t == 0) {
    const float tt = fin[0], nn = fin[1], qq = fin[2];
    float cv = 0.f, fl = 0.f;
    if (nn > 1.0f) {
      cv = (qq - tt / nn) / (nn * (float)CC);
      fl = 1.f;
    }
    atomicAdd(&acc[0], cv);
    atomicAdd(&acc[1], fl);
    __threadfence();
    const unsigned int old = atomicAdd((unsigned int*)&acc[2], 1u);
    if (old == (unsigned int)(CC - 1)) {   // last block: finalize
      const float total = atomicAdd(&acc[0], 0.f);
      const float count = atomicAdd(&acc[1], 0.f);
      out[0] = (count > 0.f) ? total / fmaxf(count, 1.f) : 0.f;
    }
  }
}

// =================== launch =================================================
extern "C" void kernel_launch(void* const* d_in, const int* in_sizes, int n_in,
                              void* d_out, int out_size, void* d_ws,
                              size_t ws_size, hipStream_t stream) {
  const float* logits = (const float*)d_in[0];
  const int* seg = (const int*)d_in[1];
  const int* mask = (const int*)d_in[2];
  float* out = (float*)d_out;

  // ws layout (16.8 MB; harness provides ~268 MB):
  // slab_s f32[256][128][128] | slab_n f32[128][256] | slab_q f32[128][256] |
  // acc f32[4] (total, count, done-ticket, pad) — zeroed by fused block 0.
  float* slab_s = (float*)d_ws;
  float* slab_n = slab_s + (size_t)NB * CC * CC;
  float* slab_q = slab_n + CC * NB;
  float* acc = slab_q + CC * NB;
  fused_kernel<<<NB, 1024, 0, stream>>>(logits, seg, mask, slab_s, slab_n,
                                        slab_q, acc);
  k3_colvar<<<CC, 1024, 0, stream>>>(slab_s, slab_n, slab_q, acc, out);
}